// Round 6
// baseline (484.939 us; speedup 1.0000x reference)
//
#include <hip/hip_runtime.h>
#include <hip/hip_bf16.h>

typedef unsigned short u16;
typedef unsigned int   u32;

// Problem constants
#define N_PIXELS 262144
#define N_COMP   1000
#define NNZ      400000
#define N_BG     2
#define BATCH    128

// ---- fused single-pass design (round 6) ----
// Entries binned by 512-pixel chunk; fused kernel holds a full [N_COMP x 8]
// f32 accumulator in LDS and makes ONE pass over X (f32), staging each
// 512-pixel x 8-batch tile transposed in LDS. Removes the bf16 XT (67 MB
// write + ~170 MB re-read) and the strided-read second pass entirely.

#define CHUNK_PX   512                        // pixels per bin/chunk
#define NBIN       (N_PIXELS / CHUNK_PX)      // 512
#define BINCAP     1024                       // mean 781 + 8.7 sigma
#define BIN_NB     128                        // binning blocks
#define BIN_CHUNK  ((NNZ + BIN_NB - 1) / BIN_NB)   // 3125
#define FB_RNG     32                         // pixel ranges (16 chunks each)
#define FB_BT      16                         // batch tiles of 8
#define CHUNKS_PER_RNG (NBIN / FB_RNG)        // 16

#define CNT_PAD 16                            // one counter per 64 B line

// ws layout (bytes)
#define WS_BCNT   0                                        // int[NBIN*16] (32 KB)
#define WS_BSLOT  32768                                    // int2[NBIN*BINCAP] (4 MB)
#define WS_NEED   (WS_BSLOT + (size_t)NBIN * BINCAP * 8)

// ---------------- bin: hierarchical binning of COO entries by pixel chunk ----
// 128 blocks x 3125 entries. LDS histogram over 512 bins -> one global atomic
// per (bin, block) -> LDS position assign. Entry packed: (col<<9)|(row&511),
// val pre-scaled by 1/nAtA.

__global__ __launch_bounds__(256) void bin_kernel(
    const int*   __restrict__ rows, const int* __restrict__ cols,
    const float* __restrict__ vals, const float* __restrict__ nAtA,
    int* __restrict__ bcnt, int2* __restrict__ bslot)
{
    __shared__ int hist[NBIN];
    __shared__ int base[NBIN];
    const int tid = threadIdx.x;

    for (int i = tid; i < NBIN; i += 256) hist[i] = 0;
    __syncthreads();

    const int e0 = blockIdx.x * BIN_CHUNK;
    const int e1 = (e0 + BIN_CHUNK < NNZ) ? (e0 + BIN_CHUNK) : NNZ;

    for (int j = e0 + tid; j < e1; j += 256)
        atomicAdd(&hist[rows[j] >> 9], 1);
    __syncthreads();

    for (int i = tid; i < NBIN; i += 256) {
        const int h = hist[i];
        base[i] = h ? atomicAdd(&bcnt[i * CNT_PAD], h) : 0;
        hist[i] = 0;                          // reuse as within-block offset
    }
    __syncthreads();

    const float inv = 1.0f / nAtA[0];
    for (int j = e0 + tid; j < e1; j += 256) {
        const int r   = rows[j];
        const int bin = r >> 9;
        const int pos = base[bin] + atomicAdd(&hist[bin], 1);
        if (pos < BINCAP) {
            int2 e;
            e.x = (cols[j] << 9) | (r & 511);
            e.y = __float_as_int(vals[j] * inv);
            bslot[(size_t)bin * BINCAP + pos] = e;
        }
    }
}

// ---------------- fused: one pass over X, LDS-resident accumulator ----------
// Grid: FB_RNG x FB_BT = 512 blocks, 256 threads (4 waves), ~62.6 KB LDS
// (2 blocks/CU). Block (rng, bt): batches b0..b0+7, pixels rng*8192..+8191 in
// 16 chunks of 512. Per chunk: stage X[8][512] -> xs[p*9+b] (f32, pad-9);
// bg accumulated from staged registers; inner loop: 8 entries/wave-iter,
// 8 lanes/entry (one per batch), ds_add_f32 into acc[c*9+b]. Epilogue: one
// global-atomic pass of acc + shuffle-reduced bg.

__global__ __launch_bounds__(256) void fused_kernel(
    const float* __restrict__ X,
    const float* __restrict__ bmat,
    const float* __restrict__ nAtA,
    const int*   __restrict__ bcnt,
    const int2*  __restrict__ bslot,
    float* __restrict__ Y)
{
    __shared__ float xs[CHUNK_PX * 9];        // 18432 B
    __shared__ float acc[N_COMP * 9];         // 36000 B
    __shared__ int2  ent[BINCAP];             //  8192 B

    const int tid  = threadIdx.x;
    const int rng  = blockIdx.x >> 4;         // / FB_BT
    const int bt   = blockIdx.x & 15;
    const int b0   = bt * 8;
    const int bq   = tid >> 5;                // batch row 0..7 (stage/bg)
    const int qq   = tid & 31;                // pixel slot (stage)
    const int wave = tid >> 6;
    const int lane = tid & 63;
    const int sub  = lane >> 3;               // entry slot in wave (0..7)
    const int bb   = lane & 7;                // batch lane (inner)

    for (int i = tid; i < N_COMP * 9; i += 256) acc[i] = 0.0f;

    const float*  xrow = X + (size_t)(b0 + bq) * N_PIXELS;
    const float4* bm4  = (const float4*)bmat; // {g0(p),g1(p),g0(p+1),g1(p+1)}
    float bg0 = 0.0f, bg1 = 0.0f;

    for (int cc = 0; cc < CHUNKS_PER_RNG; ++cc) {
        const int bin = rng * CHUNKS_PER_RNG + cc;
        const int p0  = bin * CHUNK_PX;
        int nb = bcnt[bin * CNT_PAD]; if (nb > BINCAP) nb = BINCAP;

        __syncthreads();                      // protect xs/ent from prev chunk

        // stage X chunk (4 float4 in flight) + bg from registers
        float4 t4[4];
#pragma unroll
        for (int i = 0; i < 4; ++i)
            t4[i] = *(const float4*)(xrow + p0 + 4 * (qq + 32 * i));
#pragma unroll
        for (int i = 0; i < 4; ++i) {
            const int pb = 4 * (qq + 32 * i);
            const float* tf = (const float*)&t4[i];
#pragma unroll
            for (int j = 0; j < 4; ++j)
                xs[(pb + j) * 9 + bq] = tf[j];
#pragma unroll
            for (int jj = 0; jj < 2; ++jj) {  // 2 pixels per float4 of bmat
                const float4 g = bm4[(p0 + pb) / 2 + jj];
                bg0 += g.x * tf[2 * jj]     + g.z * tf[2 * jj + 1];
                bg1 += g.y * tf[2 * jj]     + g.w * tf[2 * jj + 1];
            }
        }
        for (int i = tid; i < nb; i += 256)
            ent[i] = bslot[(size_t)bin * BINCAP + i];
        __syncthreads();

        // inner: 8 entries per wave-iteration, 8 lanes (batches) per entry
        for (int e = wave * 8 + sub; e < nb; e += 32) {
            const int2  en = ent[e];          // LDS broadcast within 8 lanes
            const float v  = __int_as_float(en.y);
            const int   rl = en.x & 511;
            const int   c  = en.x >> 9;
            atomicAdd(&acc[c * 9 + bb], v * xs[rl * 9 + bb]);
        }
    }
    __syncthreads();

    // epilogue: components
    for (int i = tid; i < N_COMP * 8; i += 256) {
        const int c = i >> 3, b = i & 7;
        const float a = acc[c * 9 + b];
        if (a != 0.0f) atomicAdd(&Y[(size_t)c * BATCH + b0 + b], a);
    }
    // epilogue: bg (reduce across the 32 lanes sharing bq)
#pragma unroll
    for (int off = 16; off; off >>= 1) {
        bg0 += __shfl_down(bg0, off, 32);
        bg1 += __shfl_down(bg1, off, 32);
    }
    if ((lane & 31) == 0) {
        const float inv = 1.0f / nAtA[0];
        float* Ybg = Y + (size_t)N_COMP * BATCH;
        atomicAdd(&Ybg[b0 + bq],         bg0 * inv);
        atomicAdd(&Ybg[BATCH + b0 + bq], bg1 * inv);
    }
}

// ---------------- fallback path (ws too small) ----------------

#define NB          8
#define NNZ_CHUNKS  64
#define CHUNK_SZ    ((NNZ + NNZ_CHUNKS - 1) / NNZ_CHUNKS)

__global__ __launch_bounds__(256) void fb_hist_kernel(
    const float* __restrict__ X, const float* __restrict__ vals,
    const int* __restrict__ rows, const int* __restrict__ cols,
    const float* __restrict__ nAtA, float* __restrict__ Y)
{
    __shared__ float hist[NB * N_COMP];
    const int tid = threadIdx.x, chunk = blockIdx.x, b0 = blockIdx.y * NB;
    for (int i = tid; i < NB * N_COMP; i += 256) hist[i] = 0.0f;
    __syncthreads();
    const float inv = 1.0f / nAtA[0];
    const int e0 = chunk * CHUNK_SZ;
    const int e1 = (e0 + CHUNK_SZ < NNZ) ? (e0 + CHUNK_SZ) : NNZ;
    const float* Xb = X + (size_t)b0 * N_PIXELS;
    for (int j = e0 + tid; j < e1; j += 256) {
        const int r = rows[j], c = cols[j];
        const float v = vals[j] * inv;
        float x[NB];
#pragma unroll
        for (int k = 0; k < NB; ++k) x[k] = Xb[(size_t)k * N_PIXELS + r];
#pragma unroll
        for (int k = 0; k < NB; ++k) atomicAdd(&hist[k * N_COMP + c], v * x[k]);
    }
    __syncthreads();
    for (int i = tid; i < N_COMP * NB; i += 256) {
        const int c = i >> 3, k = i & 7;
        atomicAdd(&Y[(size_t)c * BATCH + b0 + k], hist[k * N_COMP + c]);
    }
}

__global__ __launch_bounds__(256) void fb_bg_kernel(
    const float* __restrict__ X, const float* __restrict__ bmat,
    const float* __restrict__ nAtA, float* __restrict__ Y)
{
    const int b = blockIdx.x, chunk = blockIdx.y, tid = threadIdx.x;
    const int p0 = chunk * (N_PIXELS / 8);
    const float4* X4 = (const float4*)(X + (size_t)b * N_PIXELS + p0);
    const float4* B4 = (const float4*)(bmat + (size_t)p0 * N_BG);
    float s0 = 0.0f, s1 = 0.0f;
    for (int i = tid; i < (N_PIXELS / 8) / 4; i += 256) {
        const float4 x = X4[i];
        const float4 g0 = B4[2 * i], g1 = B4[2 * i + 1];
        s0 += x.x * g0.x + x.y * g0.z + x.z * g1.x + x.w * g1.z;
        s1 += x.x * g0.y + x.y * g0.w + x.z * g1.y + x.w * g1.w;
    }
#pragma unroll
    for (int off = 32; off > 0; off >>= 1) {
        s0 += __shfl_down(s0, off, 64);
        s1 += __shfl_down(s1, off, 64);
    }
    if ((tid & 63) == 0) {
        const float inv = 1.0f / nAtA[0];
        atomicAdd(&Y[(size_t)N_COMP * BATCH + b],       s0 * inv);
        atomicAdd(&Y[(size_t)(N_COMP + 1) * BATCH + b], s1 * inv);
    }
}

// ---------------- launch ----------------

extern "C" void kernel_launch(void* const* d_in, const int* in_sizes, int n_in,
                              void* d_out, int out_size, void* d_ws, size_t ws_size,
                              hipStream_t stream) {
    const float* X     = (const float*)d_in[0];
    const float* Avals = (const float*)d_in[1];
    const float* bmat  = (const float*)d_in[2];
    const float* nAtA  = (const float*)d_in[3];
    const int*   Arows = (const int*)d_in[4];
    const int*   Acols = (const int*)d_in[5];
    float*       Y     = (float*)d_out;

    if (ws_size >= WS_NEED) {
        char* ws = (char*)d_ws;
        int*  bcnt  = (int*)(ws + WS_BCNT);
        int2* bslot = (int2*)(ws + WS_BSLOT);

        hipMemsetAsync(bcnt, 0, NBIN * CNT_PAD * sizeof(int), stream);
        hipMemsetAsync(d_out, 0, (size_t)out_size * sizeof(float), stream);

        bin_kernel<<<BIN_NB, 256, 0, stream>>>(
            Arows, Acols, Avals, nAtA, bcnt, bslot);
        fused_kernel<<<FB_RNG * FB_BT, 256, 0, stream>>>(
            X, bmat, nAtA, bcnt, bslot, Y);
    } else {
        hipMemsetAsync(d_out, 0, (size_t)out_size * sizeof(float), stream);
        dim3 sgrid(NNZ_CHUNKS, BATCH / NB);
        fb_hist_kernel<<<sgrid, 256, 0, stream>>>(X, Avals, Arows, Acols, nAtA, Y);
        dim3 bgrid(BATCH, 8);
        fb_bg_kernel<<<bgrid, 256, 0, stream>>>(X, bmat, nAtA, Y);
    }
}

// Round 7
// 283.568 us; speedup vs baseline: 1.7101x; 1.7101x over previous
//
#include <hip/hip_runtime.h>
#include <hip/hip_bf16.h>

typedef unsigned short u16;
typedef unsigned int   u32;

// Problem constants
#define N_PIXELS 262144
#define N_COMP   1000
#define NNZ      400000
#define N_BG     2
#define BATCH    128

// Fast path config
#define CAP        576                        // slots per component (8.8 sigma over Poisson(400))
#define TP_PIX     128                        // pixels per transpose tile
#define TP_B       32                         // batches per transpose tile
#define TS         132                        // LDS row stride in floats (f4-aligned, pack 2-way free)
#define TP_BLOCKS  ((N_PIXELS / TP_PIX) * (BATCH / TP_B))  // 2048 * 4 = 8192
#define SC_NB      64                         // fat scatter blocks (hierarchical alloc)
#define SC_CHUNK   ((NNZ + SC_NB - 1) / SC_NB) // 6250 entries per scatter block
#define QMAX       ((CAP + 3) / 4)            // 144 = 9*16, entries per comp-quarter
#define BG_BLOCKS  256
#define BG_PPB     (N_PIXELS / BG_BLOCKS)     // 1024

#define CNT_PAD 16                            // one counter per 64 B line

// ws layout (bytes)
#define WS_CNT    0                                        // int[N_COMP*16] (64 KB)
#define WS_SLOTS  65536                                    // int2[N_COMP*CAP] (4.608 MB)
#define WS_XT     (WS_SLOTS + (size_t)N_COMP * CAP * 8)    // bf16[N_PIXELS][128] (67.1 MB)
#define WS_NEED   (WS_XT + (size_t)N_PIXELS * BATCH * 2)

__device__ __forceinline__ float bflo(u32 w) { return __uint_as_float(w << 16); }
__device__ __forceinline__ float bfhi(u32 w) { return __uint_as_float(w & 0xffff0000u); }

// ---------------- pre: hierarchical scatter + page-wide transpose ----------------
// blocks [0, SC_NB): 6250 COO entries each (LDS histogram -> one global atomic
//   per (comp, block) -> LDS position assign).
// blocks [SC_NB, +TP_BLOCKS): transpose tile = 32 batches x 128 pixels.
//   Round-7 theory: the ~85 us transpose wall is DRAM-page-granularity-bound.
//   Refuted: MLP (r4: reg staging, ~0), occupancy (r1: 17% vs 73% identical),
//   atomics (r2), channel spread (r3: hurt). Never tested: 512 B/row page
//   touches WITH MLP=4 AND 8 blocks/CU simultaneously. This tile does that:
//   16.9 KB LDS (8 blk/CU), 4 float4/thread staged in regs, 512 B contiguous
//   per X row. Write side: 64 B sectors; 4 consecutive blocks (bt 0..3, same
//   pixels) co-resident -> L2 merges full 256 B XT lines.
//   LDS: stride 132 f32. Stage b128: 8-lane row-group hits 32 distinct banks.
//   Pack b32: lanes = 32 pixels x 2 -> 2-way (free).

__global__ __launch_bounds__(256, 6) void pre_kernel(
    const float* __restrict__ X,
    const int*   __restrict__ rows, const int* __restrict__ cols,
    const float* __restrict__ vals, const float* __restrict__ nAtA,
    int* __restrict__ cnts, int2* __restrict__ slots,
    u32* __restrict__ XT32)                   // [N_PIXELS][64] u32
{
    __shared__ float xs[TP_B * TS];           // 16896 B (scatter branch reuses 8 KB)
    const int tid = threadIdx.x;

    if (blockIdx.x < SC_NB) {
        int* hist = (int*)xs;                 // [N_COMP]
        int* base = hist + N_COMP;            // [N_COMP]
        for (int i = tid; i < N_COMP; i += 256) hist[i] = 0;
        __syncthreads();

        const int e0 = blockIdx.x * SC_CHUNK;
        const int e1 = (e0 + SC_CHUNK < NNZ) ? (e0 + SC_CHUNK) : NNZ;

        for (int j = e0 + tid; j < e1; j += 256)
            atomicAdd(&hist[cols[j]], 1);
        __syncthreads();

        for (int c = tid; c < N_COMP; c += 256) {
            const int h = hist[c];
            base[c] = (h > 0) ? atomicAdd(&cnts[c * CNT_PAD], h) : 0;
            hist[c] = 0;                      // reuse as within-block offset
        }
        __syncthreads();

        const float inv = 1.0f / nAtA[0];
        for (int j = e0 + tid; j < e1; j += 256) {
            const int c   = cols[j];
            const int pos = base[c] + atomicAdd(&hist[c], 1);
            if (pos < CAP) {
                int2 e;
                e.x = rows[j];
                e.y = __float_as_int(vals[j] * inv);
                slots[(size_t)c * CAP + pos] = e;
            }
        }
    } else {
        const int tb = blockIdx.x - SC_NB;    // 0..8191
        const int pb = tb >> 2;               // pixel block 0..2047
        const int bt = tb & 3;                // batch tile 0..3
        const int p0 = pb * TP_PIX;
        const int b0 = bt * TP_B;

        // ---- stage: rows b0+r, 512 B contiguous each, 4 f4 in flight ----
        const int r = tid >> 3;               // 0..31 batch row
        const int k = tid & 7;                // lane within row
        const float* src = X + (size_t)(b0 + r) * N_PIXELS + p0;
        float4 t4[4];
#pragma unroll
        for (int j = 0; j < 4; ++j)
            t4[j] = *(const float4*)(src + 4 * (k + 8 * j));
#pragma unroll
        for (int j = 0; j < 4; ++j)
            *(float4*)&xs[r * TS + 4 * (k + 8 * j)] = t4[j];
        __syncthreads();

        // ---- pack: pixel p = tid>>1, rows 16h..16h+15 (h = tid&1) ----
        const int p = tid >> 1;
        const int h = tid & 1;
        u32 out[8];
#pragma unroll
        for (int q = 0; q < 8; ++q) {
            const float lo = xs[(16 * h + 2 * q)     * TS + p];
            const float hi = xs[(16 * h + 2 * q + 1) * TS + p];
            __hip_bfloat162 h2 = __float22bfloat162_rn(make_float2(lo, hi));
            u32 w; __builtin_memcpy(&w, &h2, 4);
            out[q] = w;
        }
        uint4* dst = (uint4*)(XT32 + (size_t)(p0 + p) * 64 + (b0 >> 1) + 8 * h);
        dst[0] = make_uint4(out[0], out[1], out[2], out[3]);
        dst[1] = make_uint4(out[4], out[5], out[6], out[7]);
    }
}

// ---------------- compute: comp quarters + bg ----------------
// blocks [0, 4*N_COMP): component blk>>2, quarter blk&3. 256 thr = 4 waves.
//   group g = tid>>4 owns entry stream; s = tid&15 owns batches 8s..8s+7.
// blocks [4*N_COMP, +BG_BLOCKS): background term.
// Measured ~20 us (round-5/6 accounting) at ~5 TB/s effective on L3-resident
// gathers -- near-optimal, unchanged.

__global__ __launch_bounds__(256) void compute_kernel(
    const uint4* __restrict__ XP4,            // [N_PIXELS][16] uint4
    const int*   __restrict__ cnts,
    const int2*  __restrict__ slots,
    const float* __restrict__ bmat,
    const float* __restrict__ nAtA,
    float* __restrict__ Y)
{
    __shared__ char smem_raw[12544];
    const int tid  = threadIdx.x;
    const int wave = tid >> 6;
    const int lane = tid & 63;
    const int g    = tid >> 4;
    const int s    = tid & 15;
    const int blk  = blockIdx.x;

    if (blk < 4 * N_COMP) {
        const int comp = blk >> 2;
        const int qr   = blk & 3;

        int*   sro = (int*)smem_raw;                       // [QMAX] row*16
        float* svv = (float*)(sro + QMAX);                 // [QMAX]
        float* red = (float*)(svv + QMAX);                 // [4][128]

        int cnt = cnts[comp * CNT_PAD]; if (cnt > CAP) cnt = CAP;
        const int per = (cnt + 3) >> 2;
        const int beg = qr * per;
        int end = beg + per; if (end > cnt) end = cnt;
        const int n = (end > beg) ? (end - beg) : 0;       // <= 144
        const int n_pad = (n + 15) & ~15;

        const int2* sl = slots + (size_t)comp * CAP + beg;
        for (int i = tid; i < n_pad; i += 256) {
            int r = 0; float v = 0.0f;
            if (i < n) { const int2 e = sl[i]; r = e.x; v = __int_as_float(e.y); }
            sro[i] = r << 4;
            svv[i] = v;
        }
        __syncthreads();

        float acc[8] = {0, 0, 0, 0, 0, 0, 0, 0};
        int i = 0;
        for (; i + 32 <= n_pad; i += 32) {
            const int   e0 = i + g;
            const int   e1 = i + 16 + g;
            const int   r0 = sro[e0];
            const int   r1 = sro[e1];
            const float v0 = svv[e0];
            const float v1 = svv[e1];
            const uint4 x0 = XP4[r0 + s];
            const uint4 x1 = XP4[r1 + s];
            acc[0] += v0 * bflo(x0.x); acc[1] += v0 * bfhi(x0.x);
            acc[2] += v0 * bflo(x0.y); acc[3] += v0 * bfhi(x0.y);
            acc[4] += v0 * bflo(x0.z); acc[5] += v0 * bfhi(x0.z);
            acc[6] += v0 * bflo(x0.w); acc[7] += v0 * bfhi(x0.w);
            acc[0] += v1 * bflo(x1.x); acc[1] += v1 * bfhi(x1.x);
            acc[2] += v1 * bflo(x1.y); acc[3] += v1 * bfhi(x1.y);
            acc[4] += v1 * bflo(x1.z); acc[5] += v1 * bfhi(x1.z);
            acc[6] += v1 * bflo(x1.w); acc[7] += v1 * bfhi(x1.w);
        }
        for (; i < n_pad; i += 16) {
            const int   e = i + g;
            const float v = svv[e];
            const uint4 x = XP4[sro[e] + s];               // 256 B per 16-lane group
            acc[0] += v * bflo(x.x); acc[1] += v * bfhi(x.x);
            acc[2] += v * bflo(x.y); acc[3] += v * bfhi(x.y);
            acc[4] += v * bflo(x.z); acc[5] += v * bfhi(x.z);
            acc[6] += v * bflo(x.w); acc[7] += v * bfhi(x.w);
        }
#pragma unroll
        for (int m = 16; m <= 32; m <<= 1)
#pragma unroll
            for (int q = 0; q < 8; ++q) acc[q] += __shfl_xor(acc[q], m, 64);
        if (lane < 16)
#pragma unroll
            for (int q = 0; q < 8; ++q) red[wave * 128 + lane * 8 + q] = acc[q];
        __syncthreads();
        if (tid < 128) {
            const float r0 = red[tid] + red[128 + tid] + red[256 + tid] + red[384 + tid];
            atomicAdd(&Y[(size_t)comp * BATCH + tid], r0);
        }
    } else {
        float2* bb   = (float2*)smem_raw;                  // [1024] b columns (8 KB)
        float*  red0 = (float*)(bb + BG_PPB);              // [4][128]
        float*  red1 = red0 + 512;                         // [4][128]

        const int p0 = (blk - 4 * N_COMP) * BG_PPB;
        const float2* bm2 = (const float2*)bmat;
        for (int i = tid; i < BG_PPB; i += 256) bb[i] = bm2[p0 + i];
        __syncthreads();

        float a0[8] = {0,0,0,0,0,0,0,0}, a1[8] = {0,0,0,0,0,0,0,0};
#pragma unroll 2
        for (int i = g; i < BG_PPB; i += 16) {
            const uint4  x  = XP4[(size_t)(p0 + i) * 16 + s];
            const float2 b2 = bb[i];
            const float f0 = bflo(x.x), f1 = bfhi(x.x), f2 = bflo(x.y), f3 = bfhi(x.y);
            const float f4 = bflo(x.z), f5 = bfhi(x.z), f6 = bflo(x.w), f7 = bfhi(x.w);
            a0[0] += b2.x * f0; a0[1] += b2.x * f1; a0[2] += b2.x * f2; a0[3] += b2.x * f3;
            a0[4] += b2.x * f4; a0[5] += b2.x * f5; a0[6] += b2.x * f6; a0[7] += b2.x * f7;
            a1[0] += b2.y * f0; a1[1] += b2.y * f1; a1[2] += b2.y * f2; a1[3] += b2.y * f3;
            a1[4] += b2.y * f4; a1[5] += b2.y * f5; a1[6] += b2.y * f6; a1[7] += b2.y * f7;
        }
#pragma unroll
        for (int m = 16; m <= 32; m <<= 1)
#pragma unroll
            for (int q = 0; q < 8; ++q) {
                a0[q] += __shfl_xor(a0[q], m, 64);
                a1[q] += __shfl_xor(a1[q], m, 64);
            }
        if (lane < 16)
#pragma unroll
            for (int q = 0; q < 8; ++q) {
                red0[wave * 128 + lane * 8 + q] = a0[q];
                red1[wave * 128 + lane * 8 + q] = a1[q];
            }
        __syncthreads();
        if (tid < 128) {
            const float inv = 1.0f / nAtA[0];
            float* Ybg = Y + (size_t)N_COMP * BATCH;
            const float r0 = red0[tid] + red0[128 + tid] + red0[256 + tid] + red0[384 + tid];
            const float r1 = red1[tid] + red1[128 + tid] + red1[256 + tid] + red1[384 + tid];
            atomicAdd(&Ybg[tid],         r0 * inv);
            atomicAdd(&Ybg[BATCH + tid], r1 * inv);
        }
    }
}

// ---------------- fallback path (ws too small) ----------------

#define NB          8
#define NNZ_CHUNKS  64
#define CHUNK_SZ    ((NNZ + NNZ_CHUNKS - 1) / NNZ_CHUNKS)

__global__ __launch_bounds__(256) void fb_hist_kernel(
    const float* __restrict__ X, const float* __restrict__ vals,
    const int* __restrict__ rows, const int* __restrict__ cols,
    const float* __restrict__ nAtA, float* __restrict__ Y)
{
    __shared__ float hist[NB * N_COMP];
    const int tid = threadIdx.x, chunk = blockIdx.x, b0 = blockIdx.y * NB;
    for (int i = tid; i < NB * N_COMP; i += 256) hist[i] = 0.0f;
    __syncthreads();
    const float inv = 1.0f / nAtA[0];
    const int e0 = chunk * CHUNK_SZ;
    const int e1 = (e0 + CHUNK_SZ < NNZ) ? (e0 + CHUNK_SZ) : NNZ;
    const float* Xb = X + (size_t)b0 * N_PIXELS;
    for (int j = e0 + tid; j < e1; j += 256) {
        const int r = rows[j], c = cols[j];
        const float v = vals[j] * inv;
        float x[NB];
#pragma unroll
        for (int k = 0; k < NB; ++k) x[k] = Xb[(size_t)k * N_PIXELS + r];
#pragma unroll
        for (int k = 0; k < NB; ++k) atomicAdd(&hist[k * N_COMP + c], v * x[k]);
    }
    __syncthreads();
    for (int i = tid; i < N_COMP * NB; i += 256) {
        const int c = i >> 3, k = i & 7;
        atomicAdd(&Y[(size_t)c * BATCH + b0 + k], hist[k * N_COMP + c]);
    }
}

__global__ __launch_bounds__(256) void fb_bg_kernel(
    const float* __restrict__ X, const float* __restrict__ bmat,
    const float* __restrict__ nAtA, float* __restrict__ Y)
{
    const int b = blockIdx.x, chunk = blockIdx.y, tid = threadIdx.x;
    const int p0 = chunk * (N_PIXELS / 8);
    const float4* X4 = (const float4*)(X + (size_t)b * N_PIXELS + p0);
    const float4* B4 = (const float4*)(bmat + (size_t)p0 * N_BG);
    float s0 = 0.0f, s1 = 0.0f;
    for (int i = tid; i < (N_PIXELS / 8) / 4; i += 256) {
        const float4 x = X4[i];
        const float4 g0 = B4[2 * i], g1 = B4[2 * i + 1];
        s0 += x.x * g0.x + x.y * g0.z + x.z * g1.x + x.w * g1.z;
        s1 += x.x * g0.y + x.y * g0.w + x.z * g1.y + x.w * g1.w;
    }
#pragma unroll
    for (int off = 32; off > 0; off >>= 1) {
        s0 += __shfl_down(s0, off, 64);
        s1 += __shfl_down(s1, off, 64);
    }
    if ((tid & 63) == 0) {
        const float inv = 1.0f / nAtA[0];
        atomicAdd(&Y[(size_t)N_COMP * BATCH + b],       s0 * inv);
        atomicAdd(&Y[(size_t)(N_COMP + 1) * BATCH + b], s1 * inv);
    }
}

// ---------------- launch ----------------

extern "C" void kernel_launch(void* const* d_in, const int* in_sizes, int n_in,
                              void* d_out, int out_size, void* d_ws, size_t ws_size,
                              hipStream_t stream) {
    const float* X     = (const float*)d_in[0];
    const float* Avals = (const float*)d_in[1];
    const float* bmat  = (const float*)d_in[2];
    const float* nAtA  = (const float*)d_in[3];
    const int*   Arows = (const int*)d_in[4];
    const int*   Acols = (const int*)d_in[5];
    float*       Y     = (float*)d_out;

    if (ws_size >= WS_NEED) {
        char* ws = (char*)d_ws;
        int*  cnts  = (int*)(ws + WS_CNT);
        int2* slots = (int2*)(ws + WS_SLOTS);
        u32*  XT32  = (u32*)(ws + WS_XT);

        hipMemsetAsync(cnts, 0, 65536, stream);
        hipMemsetAsync(d_out, 0, (size_t)out_size * sizeof(float), stream);

        pre_kernel<<<SC_NB + TP_BLOCKS, 256, 0, stream>>>(
            X, Arows, Acols, Avals, nAtA, cnts, slots, XT32);
        compute_kernel<<<4 * N_COMP + BG_BLOCKS, 256, 0, stream>>>(
            (const uint4*)XT32, cnts, slots, bmat, nAtA, Y);
    } else {
        hipMemsetAsync(d_out, 0, (size_t)out_size * sizeof(float), stream);
        dim3 sgrid(NNZ_CHUNKS, BATCH / NB);
        fb_hist_kernel<<<sgrid, 256, 0, stream>>>(X, Avals, Arows, Acols, nAtA, Y);
        dim3 bgrid(BATCH, 8);
        fb_bg_kernel<<<bgrid, 256, 0, stream>>>(X, bmat, nAtA, Y);
    }
}

// Round 8
// 267.922 us; speedup vs baseline: 1.8100x; 1.0584x over previous
//
#include <hip/hip_runtime.h>
#include <hip/hip_bf16.h>

typedef unsigned short u16;
typedef unsigned int   u32;

// Problem constants
#define N_PIXELS 262144
#define N_COMP   1000
#define NNZ      400000
#define N_BG     2
#define BATCH    128

// Fast path config
#define CAP        576                        // slots per component (8.8 sigma over Poisson(400))
#define TP_PIX     32                         // pixels per transpose tile
#define TP_BLOCKS  (N_PIXELS / TP_PIX)        // 8192
#define SC_NB      64                         // fat scatter blocks (hierarchical alloc)
#define SC_CHUNK   ((NNZ + SC_NB - 1) / SC_NB) // 6250 entries per scatter block
#define QMAX       ((CAP + 3) / 4)            // 144 = 9*16, entries per comp-quarter
#define BG_BLOCKS  256
#define BG_PPB     (N_PIXELS / BG_BLOCKS)     // 1024

#define CNT_PAD 16                            // one counter per 64 B line

// ws layout (bytes)
#define WS_CNT    0                                        // int[N_COMP*16] (64 KB)
#define WS_SLOTS  65536                                    // int2[N_COMP*CAP] (4.608 MB)
#define WS_XT     (WS_SLOTS + (size_t)N_COMP * CAP * 8)    // bf16[N_PIXELS][128] (67.1 MB)
#define WS_NEED   (WS_XT + (size_t)N_PIXELS * BATCH * 2)

__device__ __forceinline__ float bflo(u32 w) { return __uint_as_float(w << 16); }
__device__ __forceinline__ float bfhi(u32 w) { return __uint_as_float(w & 0xffff0000u); }

// async 16 B global -> LDS (direct DMA, no VGPR round-trip).
// HW writes lds_base + lane*16; global source address is per-lane.
typedef const float __attribute__((address_space(1))) gfloat;
typedef float       __attribute__((address_space(3))) sfloat;
__device__ __forceinline__ void ld_lds16(const float* g, float* s) {
    __builtin_amdgcn_global_load_lds((gfloat*)g, (sfloat*)s, 16, 0, 0);
}

// ---------------- pre: hierarchical scatter + async-DMA transpose ----------------
// blocks [0, SC_NB): 6250 COO entries each (LDS histogram -> one global atomic
//   per (comp, block) -> LDS position assign). Dispatched first -> hidden
//   under the transpose blocks (round-5's split serialized it: regression).
// blocks [SC_NB, +TP_BLOCKS): transpose tile = 128 batches x 32 pixels.
//   Round-8 fix: stage via global_load_lds. Every fused variant (r0/r2/r4/r7)
//   compiled to VGPR=16 with load->vmcnt(0)->ds_write serialization (MLP=1,
//   the ~85-100 us wall); the one clean reg-staged split (r5) ran <=80 us.
//   global_load_lds makes MLP=4/wave STRUCTURAL: 4 independent async 1 KB
//   wave-loads, no VGPRs, compiler can't reorder them into stalls.
//   LDS layout: linear [128 rows][8 granules x 16 B] == exactly the
//   base+lane*16 order the DMA writes (row = lane>>3, granule = lane&7).
//   Bank fix via pre-swizzled GLOBAL source: physical granule gph holds
//   global granule gph ^ (row>>4)  -> pack's scalar reads are exactly 2-way
//   (free, m136); stage is conflict-free by construction.

__global__ __launch_bounds__(256, 8) void pre_kernel(
    const float* __restrict__ X,
    const int*   __restrict__ rows, const int* __restrict__ cols,
    const float* __restrict__ vals, const float* __restrict__ nAtA,
    int* __restrict__ cnts, int2* __restrict__ slots,
    u32* __restrict__ XT32)                   // [N_PIXELS][64] u32
{
    __shared__ float xs[BATCH * TP_PIX];      // 16384 B (scatter branch reuses 8 KB)
    const int tid = threadIdx.x;

    if (blockIdx.x < SC_NB) {
        int* hist = (int*)xs;                 // [N_COMP]
        int* base = hist + N_COMP;            // [N_COMP]
        for (int i = tid; i < N_COMP; i += 256) hist[i] = 0;
        __syncthreads();

        const int e0 = blockIdx.x * SC_CHUNK;
        const int e1 = (e0 + SC_CHUNK < NNZ) ? (e0 + SC_CHUNK) : NNZ;

        for (int j = e0 + tid; j < e1; j += 256)
            atomicAdd(&hist[cols[j]], 1);
        __syncthreads();

        for (int c = tid; c < N_COMP; c += 256) {
            const int h = hist[c];
            base[c] = (h > 0) ? atomicAdd(&cnts[c * CNT_PAD], h) : 0;
            hist[c] = 0;                      // reuse as within-block offset
        }
        __syncthreads();

        const float inv = 1.0f / nAtA[0];
        for (int j = e0 + tid; j < e1; j += 256) {
            const int c   = cols[j];
            const int pos = base[c] + atomicAdd(&hist[c], 1);
            if (pos < CAP) {
                int2 e;
                e.x = rows[j];
                e.y = __float_as_int(vals[j] * inv);
                slots[(size_t)c * CAP + pos] = e;
            }
        }
    } else {
        const int p0 = (blockIdx.x - SC_NB) * TP_PIX;

        // ---- stage: 4 async wave-loads, rows 32j+8w..+7, swizzled source ----
        const int w    = tid >> 6;            // wave
        const int l    = tid & 63;
        const int rsub = l >> 3;              // row within wave-pass group
        const int gph  = l & 7;               // physical 16 B granule
#pragma unroll
        for (int j = 0; j < 4; ++j) {
            const int row = 32 * j + 8 * w + rsub;            // batch
            const int g   = gph ^ ((row >> 4) & 7);           // source granule
            ld_lds16(X + (size_t)row * N_PIXELS + p0 + 4 * g,
                     xs + 1024 * j + 256 * w);                // wave-uniform base
        }
        __syncthreads();                      // drains vmcnt before pack

        // ---- pack: pixel p = tid>>3, batches j0..j0+15 (j0 = (tid&7)*16) ----
        const int p  = tid >> 3;              // 0..31
        const int j0 = (tid & 7) * 16;
        const int ky = j0 >> 4;               // == (b>>4)&7 for all b in group
        const int pw = 4 * ((p >> 2) ^ ky) + (p & 3);         // physical word in row
        u32 out[8];
#pragma unroll
        for (int q = 0; q < 8; ++q) {
            const float lo = xs[(j0 + 2 * q)     * TP_PIX + pw];
            const float hi = xs[(j0 + 2 * q + 1) * TP_PIX + pw];
            __hip_bfloat162 h2 = __float22bfloat162_rn(make_float2(lo, hi));
            u32 v; __builtin_memcpy(&v, &h2, 4);
            out[q] = v;
        }
        uint4* dst = (uint4*)(XT32 + (size_t)(p0 + p) * 64 + (j0 >> 1));
        dst[0] = make_uint4(out[0], out[1], out[2], out[3]);
        dst[1] = make_uint4(out[4], out[5], out[6], out[7]);
    }
}

// ---------------- compute: comp quarters + bg ----------------
// blocks [0, 4*N_COMP): component blk>>2, quarter blk&3. 256 thr = 4 waves.
//   group g = tid>>4 owns entry stream; s = tid&15 owns batches 8s..8s+7.
// blocks [4*N_COMP, +BG_BLOCKS): background term.
// Measured ~20 us (round-5/6 accounting) -- near-optimal, unchanged.

__global__ __launch_bounds__(256) void compute_kernel(
    const uint4* __restrict__ XP4,            // [N_PIXELS][16] uint4
    const int*   __restrict__ cnts,
    const int2*  __restrict__ slots,
    const float* __restrict__ bmat,
    const float* __restrict__ nAtA,
    float* __restrict__ Y)
{
    __shared__ char smem_raw[12544];
    const int tid  = threadIdx.x;
    const int wave = tid >> 6;
    const int lane = tid & 63;
    const int g    = tid >> 4;
    const int s    = tid & 15;
    const int blk  = blockIdx.x;

    if (blk < 4 * N_COMP) {
        const int comp = blk >> 2;
        const int qr   = blk & 3;

        int*   sro = (int*)smem_raw;                       // [QMAX] row*16
        float* svv = (float*)(sro + QMAX);                 // [QMAX]
        float* red = (float*)(svv + QMAX);                 // [4][128]

        int cnt = cnts[comp * CNT_PAD]; if (cnt > CAP) cnt = CAP;
        const int per = (cnt + 3) >> 2;
        const int beg = qr * per;
        int end = beg + per; if (end > cnt) end = cnt;
        const int n = (end > beg) ? (end - beg) : 0;       // <= 144
        const int n_pad = (n + 15) & ~15;

        const int2* sl = slots + (size_t)comp * CAP + beg;
        for (int i = tid; i < n_pad; i += 256) {
            int r = 0; float v = 0.0f;
            if (i < n) { const int2 e = sl[i]; r = e.x; v = __int_as_float(e.y); }
            sro[i] = r << 4;
            svv[i] = v;
        }
        __syncthreads();

        float acc[8] = {0, 0, 0, 0, 0, 0, 0, 0};
        int i = 0;
        for (; i + 32 <= n_pad; i += 32) {
            const int   e0 = i + g;
            const int   e1 = i + 16 + g;
            const int   r0 = sro[e0];
            const int   r1 = sro[e1];
            const float v0 = svv[e0];
            const float v1 = svv[e1];
            const uint4 x0 = XP4[r0 + s];
            const uint4 x1 = XP4[r1 + s];
            acc[0] += v0 * bflo(x0.x); acc[1] += v0 * bfhi(x0.x);
            acc[2] += v0 * bflo(x0.y); acc[3] += v0 * bfhi(x0.y);
            acc[4] += v0 * bflo(x0.z); acc[5] += v0 * bfhi(x0.z);
            acc[6] += v0 * bflo(x0.w); acc[7] += v0 * bfhi(x0.w);
            acc[0] += v1 * bflo(x1.x); acc[1] += v1 * bfhi(x1.x);
            acc[2] += v1 * bflo(x1.y); acc[3] += v1 * bfhi(x1.y);
            acc[4] += v1 * bflo(x1.z); acc[5] += v1 * bfhi(x1.z);
            acc[6] += v1 * bflo(x1.w); acc[7] += v1 * bfhi(x1.w);
        }
        for (; i < n_pad; i += 16) {
            const int   e = i + g;
            const float v = svv[e];
            const uint4 x = XP4[sro[e] + s];               // 256 B per 16-lane group
            acc[0] += v * bflo(x.x); acc[1] += v * bfhi(x.x);
            acc[2] += v * bflo(x.y); acc[3] += v * bfhi(x.y);
            acc[4] += v * bflo(x.z); acc[5] += v * bfhi(x.z);
            acc[6] += v * bflo(x.w); acc[7] += v * bfhi(x.w);
        }
#pragma unroll
        for (int m = 16; m <= 32; m <<= 1)
#pragma unroll
            for (int q = 0; q < 8; ++q) acc[q] += __shfl_xor(acc[q], m, 64);
        if (lane < 16)
#pragma unroll
            for (int q = 0; q < 8; ++q) red[wave * 128 + lane * 8 + q] = acc[q];
        __syncthreads();
        if (tid < 128) {
            const float r0 = red[tid] + red[128 + tid] + red[256 + tid] + red[384 + tid];
            atomicAdd(&Y[(size_t)comp * BATCH + tid], r0);
        }
    } else {
        float2* bb   = (float2*)smem_raw;                  // [1024] b columns (8 KB)
        float*  red0 = (float*)(bb + BG_PPB);              // [4][128]
        float*  red1 = red0 + 512;                         // [4][128]

        const int p0 = (blk - 4 * N_COMP) * BG_PPB;
        const float2* bm2 = (const float2*)bmat;
        for (int i = tid; i < BG_PPB; i += 256) bb[i] = bm2[p0 + i];
        __syncthreads();

        float a0[8] = {0,0,0,0,0,0,0,0}, a1[8] = {0,0,0,0,0,0,0,0};
#pragma unroll 2
        for (int i = g; i < BG_PPB; i += 16) {
            const uint4  x  = XP4[(size_t)(p0 + i) * 16 + s];
            const float2 b2 = bb[i];
            const float f0 = bflo(x.x), f1 = bfhi(x.x), f2 = bflo(x.y), f3 = bfhi(x.y);
            const float f4 = bflo(x.z), f5 = bfhi(x.z), f6 = bflo(x.w), f7 = bfhi(x.w);
            a0[0] += b2.x * f0; a0[1] += b2.x * f1; a0[2] += b2.x * f2; a0[3] += b2.x * f3;
            a0[4] += b2.x * f4; a0[5] += b2.x * f5; a0[6] += b2.x * f6; a0[7] += b2.x * f7;
            a1[0] += b2.y * f0; a1[1] += b2.y * f1; a1[2] += b2.y * f2; a1[3] += b2.y * f3;
            a1[4] += b2.y * f4; a1[5] += b2.y * f5; a1[6] += b2.y * f6; a1[7] += b2.y * f7;
        }
#pragma unroll
        for (int m = 16; m <= 32; m <<= 1)
#pragma unroll
            for (int q = 0; q < 8; ++q) {
                a0[q] += __shfl_xor(a0[q], m, 64);
                a1[q] += __shfl_xor(a1[q], m, 64);
            }
        if (lane < 16)
#pragma unroll
            for (int q = 0; q < 8; ++q) {
                red0[wave * 128 + lane * 8 + q] = a0[q];
                red1[wave * 128 + lane * 8 + q] = a1[q];
            }
        __syncthreads();
        if (tid < 128) {
            const float inv = 1.0f / nAtA[0];
            float* Ybg = Y + (size_t)N_COMP * BATCH;
            const float r0 = red0[tid] + red0[128 + tid] + red0[256 + tid] + red0[384 + tid];
            const float r1 = red1[tid] + red1[128 + tid] + red1[256 + tid] + red1[384 + tid];
            atomicAdd(&Ybg[tid],         r0 * inv);
            atomicAdd(&Ybg[BATCH + tid], r1 * inv);
        }
    }
}

// ---------------- fallback path (ws too small) ----------------

#define NB          8
#define NNZ_CHUNKS  64
#define CHUNK_SZ    ((NNZ + NNZ_CHUNKS - 1) / NNZ_CHUNKS)

__global__ __launch_bounds__(256) void fb_hist_kernel(
    const float* __restrict__ X, const float* __restrict__ vals,
    const int* __restrict__ rows, const int* __restrict__ cols,
    const float* __restrict__ nAtA, float* __restrict__ Y)
{
    __shared__ float hist[NB * N_COMP];
    const int tid = threadIdx.x, chunk = blockIdx.x, b0 = blockIdx.y * NB;
    for (int i = tid; i < NB * N_COMP; i += 256) hist[i] = 0.0f;
    __syncthreads();
    const float inv = 1.0f / nAtA[0];
    const int e0 = chunk * CHUNK_SZ;
    const int e1 = (e0 + CHUNK_SZ < NNZ) ? (e0 + CHUNK_SZ) : NNZ;
    const float* Xb = X + (size_t)b0 * N_PIXELS;
    for (int j = e0 + tid; j < e1; j += 256) {
        const int r = rows[j], c = cols[j];
        const float v = vals[j] * inv;
        float x[NB];
#pragma unroll
        for (int k = 0; k < NB; ++k) x[k] = Xb[(size_t)k * N_PIXELS + r];
#pragma unroll
        for (int k = 0; k < NB; ++k) atomicAdd(&hist[k * N_COMP + c], v * x[k]);
    }
    __syncthreads();
    for (int i = tid; i < N_COMP * NB; i += 256) {
        const int c = i >> 3, k = i & 7;
        atomicAdd(&Y[(size_t)c * BATCH + b0 + k], hist[k * N_COMP + c]);
    }
}

__global__ __launch_bounds__(256) void fb_bg_kernel(
    const float* __restrict__ X, const float* __restrict__ bmat,
    const float* __restrict__ nAtA, float* __restrict__ Y)
{
    const int b = blockIdx.x, chunk = blockIdx.y, tid = threadIdx.x;
    const int p0 = chunk * (N_PIXELS / 8);
    const float4* X4 = (const float4*)(X + (size_t)b * N_PIXELS + p0);
    const float4* B4 = (const float4*)(bmat + (size_t)p0 * N_BG);
    float s0 = 0.0f, s1 = 0.0f;
    for (int i = tid; i < (N_PIXELS / 8) / 4; i += 256) {
        const float4 x = X4[i];
        const float4 g0 = B4[2 * i], g1 = B4[2 * i + 1];
        s0 += x.x * g0.x + x.y * g0.z + x.z * g1.x + x.w * g1.z;
        s1 += x.x * g0.y + x.y * g0.w + x.z * g1.y + x.w * g1.w;
    }
#pragma unroll
    for (int off = 32; off > 0; off >>= 1) {
        s0 += __shfl_down(s0, off, 64);
        s1 += __shfl_down(s1, off, 64);
    }
    if ((tid & 63) == 0) {
        const float inv = 1.0f / nAtA[0];
        atomicAdd(&Y[(size_t)N_COMP * BATCH + b],       s0 * inv);
        atomicAdd(&Y[(size_t)(N_COMP + 1) * BATCH + b], s1 * inv);
    }
}

// ---------------- launch ----------------

extern "C" void kernel_launch(void* const* d_in, const int* in_sizes, int n_in,
                              void* d_out, int out_size, void* d_ws, size_t ws_size,
                              hipStream_t stream) {
    const float* X     = (const float*)d_in[0];
    const float* Avals = (const float*)d_in[1];
    const float* bmat  = (const float*)d_in[2];
    const float* nAtA  = (const float*)d_in[3];
    const int*   Arows = (const int*)d_in[4];
    const int*   Acols = (const int*)d_in[5];
    float*       Y     = (float*)d_out;

    if (ws_size >= WS_NEED) {
        char* ws = (char*)d_ws;
        int*  cnts  = (int*)(ws + WS_CNT);
        int2* slots = (int2*)(ws + WS_SLOTS);
        u32*  XT32  = (u32*)(ws + WS_XT);

        hipMemsetAsync(cnts, 0, 65536, stream);
        hipMemsetAsync(d_out, 0, (size_t)out_size * sizeof(float), stream);

        pre_kernel<<<SC_NB + TP_BLOCKS, 256, 0, stream>>>(
            X, Arows, Acols, Avals, nAtA, cnts, slots, XT32);
        compute_kernel<<<4 * N_COMP + BG_BLOCKS, 256, 0, stream>>>(
            (const uint4*)XT32, cnts, slots, bmat, nAtA, Y);
    } else {
        hipMemsetAsync(d_out, 0, (size_t)out_size * sizeof(float), stream);
        dim3 sgrid(NNZ_CHUNKS, BATCH / NB);
        fb_hist_kernel<<<sgrid, 256, 0, stream>>>(X, Avals, Arows, Acols, nAtA, Y);
        dim3 bgrid(BATCH, 8);
        fb_bg_kernel<<<bgrid, 256, 0, stream>>>(X, bmat, nAtA, Y);
    }
}